// Round 6
// baseline (542.651 us; speedup 1.0000x reference)
//
#include <hip/hip_runtime.h>
#include <hip/hip_fp16.h>
#include <math.h>

#define U_NUM_ 50000
#define I_NUM_ 50000
#define EMBED_ 64
#define ATT_   64
#define NNZ_   2500000
#define TILE_  6250          // 50000/8 -> 8x8 = 64 buckets
#define NBKT_  64

// ---------------------------------------------------------------------------
// Pass 0: four 50000x64 @ 64x64^T projections, fp32 accumulate, fp16 store,
// interleaved so one edge gather serves both the ui and iu directions:
//   utab[row][  0: 64] = Qu   utab[row][ 64:128] = Ku
//   itab[col][  0: 64] = Ki   itab[col][ 64:128] = Qi
// ---------------------------------------------------------------------------
__global__ __launch_bounds__(256) void proj_kernel(
        const float* __restrict__ user_embed, const float* __restrict__ item_embed,
        const float* __restrict__ Wq, const float* __restrict__ bq,
        const float* __restrict__ Wk, const float* __restrict__ bk,
        __half* __restrict__ utab, __half* __restrict__ itab) {
    __shared__ float Wl[ATT_][EMBED_ + 1];
    __shared__ float El[32][EMBED_];
    __shared__ float bl[ATT_];

    const int combo = blockIdx.y;
    const float* E = (combo == 0 || combo == 3) ? user_embed : item_embed;
    const float* W = (combo == 0 || combo == 2) ? Wq : Wk;
    const float* b = (combo == 0 || combo == 2) ? bq : bk;
    __half* tab    = (combo == 0 || combo == 3) ? utab : itab;
    const int off  = (combo == 0 || combo == 1) ? 0 : 64;

    const int tid = threadIdx.x;

    for (int i4 = tid; i4 < 1024; i4 += 256) {
        const int r = i4 >> 4, c4 = (i4 & 15) * 4;
        float4 w = ((const float4*)W)[i4];
        Wl[r][c4 + 0] = w.x; Wl[r][c4 + 1] = w.y;
        Wl[r][c4 + 2] = w.z; Wl[r][c4 + 3] = w.w;
    }
    if (tid < ATT_) bl[tid] = b[tid];

    const int row0 = blockIdx.x * 32;
    for (int i4 = tid; i4 < 512; i4 += 256) {
        const int r = i4 >> 4, c4 = (i4 & 15) * 4;
        const int gr = row0 + r;
        float4 ev = make_float4(0.f, 0.f, 0.f, 0.f);
        if (gr < U_NUM_) ev = ((const float4*)(E + (size_t)gr * EMBED_))[i4 & 15];
        *(float4*)&El[r][c4] = ev;
    }
    __syncthreads();

    const int a  = tid & 63;
    const int rw = tid >> 6;
    float acc[8];
    #pragma unroll
    for (int k = 0; k < 8; ++k) acc[k] = bl[a];

    #pragma unroll 2
    for (int e4 = 0; e4 < 16; ++e4) {
        const float w0 = Wl[a][e4 * 4 + 0];
        const float w1 = Wl[a][e4 * 4 + 1];
        const float w2 = Wl[a][e4 * 4 + 2];
        const float w3 = Wl[a][e4 * 4 + 3];
        #pragma unroll
        for (int k = 0; k < 8; ++k) {
            float4 ev = *(const float4*)&El[rw + 4 * k][e4 * 4];
            acc[k] = fmaf(ev.x, w0, fmaf(ev.y, w1, fmaf(ev.z, w2, fmaf(ev.w, w3, acc[k]))));
        }
    }

    #pragma unroll
    for (int k = 0; k < 8; ++k) {
        const int gr = row0 + rw + 4 * k;
        if (gr < U_NUM_) tab[(size_t)gr * 128 + off + a] = __float2half(acc[k]);
    }
}

// ---------------------------------------------------------------------------
// Sort pass 1: per-bucket counts (LDS-aggregated, 64 global atomics / block).
// ---------------------------------------------------------------------------
__global__ __launch_bounds__(256) void count_kernel(
        const int* __restrict__ rows, const int* __restrict__ cols,
        unsigned* __restrict__ gcnt) {
    __shared__ unsigned cl[NBKT_];
    if (threadIdx.x < NBKT_) cl[threadIdx.x] = 0;
    __syncthreads();
    int j = blockIdx.x * blockDim.x + threadIdx.x;
    const int st = gridDim.x * blockDim.x;
    for (; j < NNZ_; j += st) {
        const int b = (rows[j] / TILE_) * 8 + cols[j] / TILE_;
        atomicAdd(&cl[b], 1u);
    }
    __syncthreads();
    if (threadIdx.x < NBKT_ && cl[threadIdx.x])
        atomicAdd(&gcnt[threadIdx.x], cl[threadIdx.x]);
}

// ---------------------------------------------------------------------------
// Sort pass 2: exclusive prefix over 64 counts -> cursor array.
// ---------------------------------------------------------------------------
__global__ void scan_kernel(const unsigned* __restrict__ gcnt,
                            unsigned* __restrict__ gcursor) {
    if (threadIdx.x == 0) {
        unsigned run = 0;
        for (int k = 0; k < NBKT_; ++k) { gcursor[k] = run; run += gcnt[k]; }
    }
}

// ---------------------------------------------------------------------------
// Sort pass 3: scatter edges into bucket-major records. Each block reserves
// per-bucket ranges once (64 atomics), so its writes form ~600 B contiguous
// runs per bucket -> coalesced. Record = {rc packed, orig j, u_ui, u_iu}.
// ---------------------------------------------------------------------------
__global__ __launch_bounds__(256) void scatter_kernel(
        const int* __restrict__ rows, const int* __restrict__ cols,
        const float* __restrict__ u_ui, const float* __restrict__ u_iu,
        unsigned* __restrict__ gcursor, uint4* __restrict__ recs) {
    __shared__ unsigned cnt[NBKT_];
    __shared__ unsigned base[NBKT_];
    const int tid = threadIdx.x;
    const int chunk = (NNZ_ + gridDim.x - 1) / gridDim.x;
    const int j0 = blockIdx.x * chunk;
    const int j1 = min(j0 + chunk, NNZ_);
    if (tid < NBKT_) cnt[tid] = 0;
    __syncthreads();
    for (int j = j0 + tid; j < j1; j += 256) {
        const int b = (rows[j] / TILE_) * 8 + cols[j] / TILE_;
        atomicAdd(&cnt[b], 1u);
    }
    __syncthreads();
    if (tid < NBKT_) {
        base[tid] = atomicAdd(&gcursor[tid], cnt[tid]);
        cnt[tid] = 0;
    }
    __syncthreads();
    for (int j = j0 + tid; j < j1; j += 256) {
        const int r = rows[j], c = cols[j];
        const int b = (r / TILE_) * 8 + c / TILE_;
        const unsigned pos = base[b] + atomicAdd(&cnt[b], 1u);
        uint4 rec;
        rec.x = ((unsigned)r << 16) | (unsigned)c;   // both < 65536
        rec.y = (unsigned)j;
        rec.z = __float_as_uint(u_ui[j]);
        rec.w = __float_as_uint(u_iu[j]);
        recs[pos] = rec;
    }
}

// ---------------------------------------------------------------------------
// Gather pass over bucket-major records: at any instant the grid's linear
// window spans ~1-2 buckets -> utab/itab slices (~3-5 MB) are L2-resident.
// 16 lanes per record, 2 consecutive records per group. Lanes 0-7: Qu·Ki
// (ui); lanes 8-15: Ku·Qi (iu). e-values stored in bucketed order
// (coalesced); segment sums via atomics.
// ---------------------------------------------------------------------------
__global__ __launch_bounds__(256) void gather_kernel(
        const uint4* __restrict__ recs,
        const __half* __restrict__ utab, const __half* __restrict__ itab,
        float* __restrict__ eo, float* __restrict__ segsum) {
    const int lane = threadIdx.x & 15;
    const int g  = (blockIdx.x * blockDim.x + threadIdx.x) >> 4;
    const int ng = (gridDim.x * blockDim.x) >> 4;
    const uint4* up = (const uint4*)utab;   // 16 x 16 B chunks per 256 B row
    const uint4* ip = (const uint4*)itab;
    const bool iu = (lane & 8) != 0;
    union H8 { uint4 u; __half2 h[4]; };

    for (int p0 = g * 2; p0 < NNZ_; p0 += ng * 2) {
        const int p1 = p0 + 1;
        const uint4 r0 = recs[p0];
        const uint4 r1 = (p1 < NNZ_) ? recs[p1] : r0;
        const int ra = r0.x >> 16, ca = r0.x & 0xffff;
        const int rb = r1.x >> 16, cb = r1.x & 0xffff;

        H8 a0, b0, a1, b1;
        a0.u = up[(size_t)ra * 16 + lane]; b0.u = ip[(size_t)ca * 16 + lane];
        a1.u = up[(size_t)rb * 16 + lane]; b1.u = ip[(size_t)cb * 16 + lane];

        float q0 = 0.f, q1 = 0.f;
        #pragma unroll
        for (int m = 0; m < 4; ++m) {
            float2 x, y;
            x = __half22float2(a0.h[m]); y = __half22float2(b0.h[m]);
            q0 = fmaf(x.x, y.x, q0); q0 = fmaf(x.y, y.y, q0);
            x = __half22float2(a1.h[m]); y = __half22float2(b1.h[m]);
            q1 = fmaf(x.x, y.x, q1); q1 = fmaf(x.y, y.y, q1);
        }
        q0 += __shfl_xor(q0, 1); q1 += __shfl_xor(q1, 1);
        q0 += __shfl_xor(q0, 2); q1 += __shfl_xor(q1, 2);
        q0 += __shfl_xor(q0, 4); q1 += __shfl_xor(q1, 4);
        // lanes 0-7 hold w_ui; lanes 8-15 hold w_iu

        const float n0 = __uint_as_float(iu ? r0.w : r0.z);
        const float n1 = __uint_as_float(iu ? r1.w : r1.z);
        const float e0 = __expf(q0 - __logf(-__logf(n0)));   // TAU = 1
        const float e1 = __expf(q1 - __logf(-__logf(n1)));

        if (lane == 0) {
            eo[p0] = e0; atomicAdd(&segsum[ra], e0);
            if (p1 < NNZ_) { eo[p1] = e1; atomicAdd(&segsum[rb], e1); }
        } else if (lane == 8) {
            eo[NNZ_ + p0] = e0; atomicAdd(&segsum[U_NUM_ + ca], e0);
            if (p1 < NNZ_) { eo[NNZ_ + p1] = e1; atomicAdd(&segsum[U_NUM_ + cb], e1); }
        }
    }
}

// ---------------------------------------------------------------------------
// Normalize + un-permute: coalesced reads of records/e-values; scattered 4 B
// final stores are NON-TEMPORAL (each address written exactly once; nt avoids
// L2 write-allocate churn on the random pattern).
// ---------------------------------------------------------------------------
__global__ __launch_bounds__(256) void norm_kernel(
        const uint4* __restrict__ recs, const float* __restrict__ eo,
        const float* __restrict__ segsum, float* __restrict__ out) {
    int t = blockIdx.x * blockDim.x + threadIdx.x;
    const int st = gridDim.x * blockDim.x;
    for (; t < NNZ_; t += st) {
        const uint4 rec = recs[t];
        const int r = rec.x >> 16, c = rec.x & 0xffff;
        const int j = (int)rec.y;
        const float oui = eo[t] / segsum[r];
        const float oiu = eo[NNZ_ + t] / segsum[U_NUM_ + c];
        __builtin_nontemporal_store(oui, &out[j]);
        __builtin_nontemporal_store(oiu, &out[NNZ_ + j]);
    }
}

// ---------------------------------------------------------------------------
// Fallback path (round-5 kernels) if workspace is too small for the sort.
// ---------------------------------------------------------------------------
__global__ __launch_bounds__(256) void edge_pass1(
        const int* __restrict__ rows, const int* __restrict__ cols,
        const float* __restrict__ u_ui, const float* __restrict__ u_iu,
        const __half* __restrict__ utab, const __half* __restrict__ itab,
        float* __restrict__ out, float* __restrict__ segsum) {
    const int lane = threadIdx.x & 15;
    const int gid  = (blockIdx.x * blockDim.x + threadIdx.x) >> 4;
    const int ngr  = (gridDim.x * blockDim.x) >> 4;
    const uint4* up = (const uint4*)utab;
    const uint4* ip = (const uint4*)itab;
    const bool iu = (lane & 8) != 0;
    const float* unoise = iu ? u_iu : u_ui;
    union H8 { uint4 u; __half2 h[4]; };

    for (int j = gid; j < NNZ_; j += ngr) {
        const int r0 = rows[j], c0 = cols[j];
        H8 a0, b0;
        a0.u = up[(size_t)r0 * 16 + lane];
        b0.u = ip[(size_t)c0 * 16 + lane];
        const float n0 = unoise[j];
        float p0 = 0.f;
        #pragma unroll
        for (int m = 0; m < 4; ++m) {
            float2 x = __half22float2(a0.h[m]), y = __half22float2(b0.h[m]);
            p0 = fmaf(x.x, y.x, p0); p0 = fmaf(x.y, y.y, p0);
        }
        p0 += __shfl_xor(p0, 1);
        p0 += __shfl_xor(p0, 2);
        p0 += __shfl_xor(p0, 4);
        const float e0 = __expf(p0 - __logf(-__logf(n0)));
        if (lane == 0)      { out[j] = e0;        atomicAdd(&segsum[r0], e0); }
        else if (lane == 8) { out[NNZ_ + j] = e0; atomicAdd(&segsum[U_NUM_ + c0], e0); }
    }
}

__global__ __launch_bounds__(256) void edge_pass2(
        const int* __restrict__ rows, const int* __restrict__ cols,
        const float* __restrict__ segsum, float* __restrict__ out) {
    int i = blockIdx.x * blockDim.x + threadIdx.x;
    const int stride = gridDim.x * blockDim.x;
    const int n4 = (2 * NNZ_) / 4;
    for (; i < n4; i += stride) {
        float4 v = ((const float4*)out)[i];
        const int base = i * 4;
        int4 seg;
        if (base < NNZ_) {
            seg = *(const int4*)(rows + base);
        } else {
            seg = *(const int4*)(cols + (base - NNZ_));
            seg.x += U_NUM_; seg.y += U_NUM_; seg.z += U_NUM_; seg.w += U_NUM_;
        }
        v.x /= segsum[seg.x];
        v.y /= segsum[seg.y];
        v.z /= segsum[seg.z];
        v.w /= segsum[seg.w];
        ((float4*)out)[i] = v;
    }
}

extern "C" void kernel_launch(void* const* d_in, const int* in_sizes, int n_in,
                              void* d_out, int out_size, void* d_ws, size_t ws_size,
                              hipStream_t stream) {
    const float* user_embed = (const float*)d_in[0];
    const float* item_embed = (const float*)d_in[1];
    const float* Wq = (const float*)d_in[2];
    const float* bq = (const float*)d_in[3];
    const float* Wk = (const float*)d_in[4];
    const float* bk = (const float*)d_in[5];
    const int*   rows = (const int*)d_in[6];
    const int*   cols = (const int*)d_in[7];
    const float* u_ui = (const float*)d_in[8];
    const float* u_iu = (const float*)d_in[9];
    float* out = (float*)d_out;

    const size_t utabB = (size_t)U_NUM_ * 128 * sizeof(__half);   // 12.8 MB
    const size_t itabB = (size_t)I_NUM_ * 128 * sizeof(__half);   // 12.8 MB
    const size_t recB  = (size_t)NNZ_ * 16;                       // 40 MB
    const size_t eoB   = (size_t)2 * NNZ_ * sizeof(float);        // 20 MB
    const size_t segB  = (size_t)(U_NUM_ + I_NUM_) * sizeof(float);
    const size_t need  = utabB + itabB + recB + eoB + segB + 2 * NBKT_ * 4;

    __half* utab = (__half*)d_ws;
    __half* itab = (__half*)((char*)d_ws + utabB);

    dim3 pgrid((U_NUM_ + 31) / 32, 4);
    proj_kernel<<<pgrid, 256, 0, stream>>>(user_embed, item_embed, Wq, bq, Wk, bk, utab, itab);

    if (ws_size >= need) {
        uint4* recs      = (uint4*)((char*)d_ws + utabB + itabB);
        float* eo        = (float*)((char*)recs + recB);
        float* segsum    = (float*)((char*)eo + eoB);
        unsigned* gcnt   = (unsigned*)((char*)segsum + segB);
        unsigned* gcursor = gcnt + NBKT_;

        hipMemsetAsync(segsum, 0, segB, stream);
        hipMemsetAsync(gcnt, 0, NBKT_ * 4, stream);

        count_kernel<<<512, 256, 0, stream>>>(rows, cols, gcnt);
        scan_kernel<<<1, 64, 0, stream>>>(gcnt, gcursor);
        scatter_kernel<<<1024, 256, 0, stream>>>(rows, cols, u_ui, u_iu, gcursor, recs);
        gather_kernel<<<1024, 256, 0, stream>>>(recs, utab, itab, eo, segsum);
        norm_kernel<<<2048, 256, 0, stream>>>(recs, eo, segsum, out);
    } else {
        float* segsum = (float*)((char*)d_ws + utabB + itabB);
        hipMemsetAsync(segsum, 0, segB, stream);
        edge_pass1<<<4096, 256, 0, stream>>>(rows, cols, u_ui, u_iu, utab, itab, out, segsum);
        edge_pass2<<<2048, 256, 0, stream>>>(rows, cols, segsum, out);
    }
}